// Round 25
// baseline (199.549 us; speedup 1.0000x reference)
//
#include <hip/hip_runtime.h>
#include <hip/hip_bf16.h>
#include <math.h>

#define NN 256
#define NSEG 32
#define MAT (NN*NN)            // 65536 floats

// float offsets inside d_ws
#define MATS0 0                        // 64 leaf matrices (U:0..31, V:32..63)
#define MATS1 (MATS0 + 64*MAT)         // 32 matrices; final U,V land here
#define WBT_OFF (MATS1 + 32*MAT)       // 65536 ushort (bf16 W^T[n][k]) = 32768 floats
#define XBF_OFF (WBT_OFF + 32768)      // 33.55M ushort (bf16 x) = 16.78M floats
#define WS_NEED_FLOATS (XBF_OFF + 16777216)

// sweep boundaries: segment g = sweeps [BD[g], BD[g+1]); nrot <= 1120.
static __device__ const int BD[NSEG+1] =
    {0,4,8,12,16,20,24,28,32,37,42,47,52,57,62,67,73,79,85,91,97,
     104,111,118,126,134,143,153,164,177,192,213,255};
#define CSL_CAP 1120

typedef __attribute__((ext_vector_type(8))) short short8;
typedef __attribute__((ext_vector_type(4))) float f32x4;

__device__ __forceinline__ short f2bf(float f) {
    __hip_bfloat16 h = __float2bfloat16(f);   // RNE
    return *reinterpret_cast<short*>(&h);
}

// Raw block barrier: flushes LDS but does NOT drain vmcnt.
#define BAR() do {                                              \
    asm volatile("s_waitcnt lgkmcnt(0)" ::: "memory");          \
    __builtin_amdgcn_s_barrier();                               \
    asm volatile("" ::: "memory");                              \
} while (0)

// Wave-local LDS fence: single-wave producer/consumer, 64-lane lockstep.
#define WAVE_LDS_FENCE() asm volatile("s_waitcnt lgkmcnt(0)" ::: "memory")

// ---------------- 1) k_build: rotations (wave 0) + x->bf16 (waves 1-7) ------
// r24 post-mortem: conv at 1.37 TB/s = 2 conv waves/CU x ~1KB in flight /
// ~375ns (compiler serializes load->cvt->store per float4); locality changes
// were null. FIX: TLP -- 512-thread blocks = 7 conv waves/CU. Even at the
// observed per-wave issue rate, 7 waves ~ 4.8 TB/s -> conv ~40us ~ rotation
// time -> hidden. Block b owns 16384 contiguous float8-units (448*36+256).
__global__ __launch_bounds__(512, 1) void k_build(const float* __restrict__ au,
                                                  const float* __restrict__ av,
                                                  float* __restrict__ mats,
                                                  const float* __restrict__ x,
                                                  unsigned short* __restrict__ xbf) {
    int b = blockIdx.x;
    int t = threadIdx.x;

    if (t >= 64) {                       // 7 conversion waves
        if (xbf != nullptr) {
            int lane = t - 64;           // 0..447
            long base = (long)b * 16384; // float8-units per block
            for (int kk = 0; kk < 36; kk += 4) {
                long e[4]; float4 a[4], c[4];
#pragma unroll
                for (int j = 0; j < 4; ++j) {
                    e[j] = (base + (long)(kk + j) * 448 + lane) * 8;
                    a[j] = *(const float4*)(x + e[j]);
                    c[j] = *(const float4*)(x + e[j] + 4);
                }
#pragma unroll
                for (int j = 0; j < 4; ++j) {
                    short8 h;
                    h[0]=f2bf(a[j].x); h[1]=f2bf(a[j].y);
                    h[2]=f2bf(a[j].z); h[3]=f2bf(a[j].w);
                    h[4]=f2bf(c[j].x); h[5]=f2bf(c[j].y);
                    h[6]=f2bf(c[j].z); h[7]=f2bf(c[j].w);
                    *(short8*)(xbf + e[j]) = h;
                }
            }
            if (lane < 256) {            // tail: 256 units per block
                long e = (base + 16128 + lane) * 8;
                float4 a = *(const float4*)(x + e);
                float4 c = *(const float4*)(x + e + 4);
                short8 h;
                h[0]=f2bf(a.x); h[1]=f2bf(a.y); h[2]=f2bf(a.z); h[3]=f2bf(a.w);
                h[4]=f2bf(c.x); h[5]=f2bf(c.y); h[6]=f2bf(c.z); h[7]=f2bf(c.w);
                *(short8*)(xbf + e) = h;
            }
        }
        return;
    }

    // ---- wave 0: rotation body (r19/r21-verified) ----
    int matid = b >> 7;          // 0=U, 1=V
    int seg   = (b >> 2) & 31;
    int chunk = b & 3;
    int c0 = chunk * 64;
    int i0 = BD[seg], i1 = BD[seg+1];
    float* outp = mats + (matid * NSEG + seg) * MAT;

    if (c0 + 64 <= i0) {         // whole chunk is identity columns
        for (int id = t; id < 4096; id += 64) {
            int row = id >> 4, c4 = (id & 15) * 4;
            float4 v = {0.f,0.f,0.f,0.f};
            int d = row - (c0 + c4);
            if (d >= 0 && d < 4) ((float*)&v)[d] = 1.0f;
            *(float4*)(outp + row*NN + c0 + c4) = v;
        }
        return;
    }

    __shared__ float M[NN * 64];       // rows [i0,256) x 64 cols
    __shared__ float2 csl[CSL_CAP];    // segment cos/sin table

    int kbase = 255*i0 - (i0*(i0-1))/2;
    int kend  = 255*i1 - (i1*(i1-1))/2;
    int nrot  = kend - kbase;
    const float* ang = (matid ? av : au) + kbase;
    for (int idx = t; idx < nrot; idx += 64) {
        float s, c;
        sincosf(ang[idx], &s, &c);
        float2 v = {c, s};
        csl[idx] = v;
    }
    int MR = NN - i0;
    for (int rr = 0; rr < MR; ++rr)
        M[rr*64 + t] = (i0 + rr == c0 + t) ? 1.0f : 0.0f;
    WAVE_LDS_FENCE();

    int i = i0;
    while (i < i1) {
        int bs = i1 - i; if (bs > 4) bs = 4;
        float r[4];
#pragma unroll
        for (int k = 0; k < 4; ++k)
            if (k < bs) r[k] = M[(i + k - i0)*64 + t];

        // head triangle (register-only), lex order, chunk-clip guard
#pragma unroll
        for (int a = 0; a < 3; ++a)
#pragma unroll
            for (int b2 = a + 1; b2 < 4; ++b2)
                if (b2 < bs && i + b2 >= c0) {
                    int aa = i + a;
                    int idx = 255*aa - (aa*(aa-1))/2 + (b2 - a - 1) - kbase;
                    float2 cs = csl[idx];
                    float wv = cs.y*r[a] + cs.x*r[b2];
                    r[a]  = cs.x*r[a] - cs.y*r[b2];
                    r[b2] = wv;
                }

        int jblk = i + bs; if (jblk < c0) jblk = c0;
        int base[4];
#pragma unroll
        for (int k = 0; k < 4; ++k) {
            int a = i + k;
            base[k] = 255*a - (a*(a-1))/2 - a - 1 - kbase;
        }

        int j = jblk;
        int ngr = (NN - jblk) >> 2;
        float rjc[4]; float2 csc[4][4];
        if (ngr > 0) {
#pragma unroll
            for (int u = 0; u < 4; ++u) rjc[u] = M[(j + u - i0)*64 + t];
#pragma unroll
            for (int k = 0; k < 4; ++k)
                if (k < bs)
#pragma unroll
                    for (int u = 0; u < 4; ++u)
                        csc[k][u] = csl[base[k] + j + u];
        }
        for (int g = 0; g < ngr; ++g) {
            float rjn[4]; float2 csn[4][4];
            if (g + 1 < ngr) {          // prefetch next column group
#pragma unroll
                for (int u = 0; u < 4; ++u) rjn[u] = M[(j + 4 + u - i0)*64 + t];
#pragma unroll
                for (int k = 0; k < 4; ++k)
                    if (k < bs)
#pragma unroll
                        for (int u = 0; u < 4; ++u)
                            csn[k][u] = csl[base[k] + j + 4 + u];
            }
#pragma unroll
            for (int u = 0; u < 4; ++u) {
                float rj = rjc[u];
#pragma unroll
                for (int k = 0; k < 4; ++k)
                    if (k < bs) {
                        float2 cs = csc[k][u];
                        float wv = cs.y*r[k] + cs.x*rj;
                        r[k] = cs.x*r[k] - cs.y*rj;
                        rj = wv;
                    }
                M[(j + u - i0)*64 + t] = rj;
            }
#pragma unroll
            for (int u = 0; u < 4; ++u) rjc[u] = rjn[u];
#pragma unroll
            for (int k = 0; k < 4; ++k)
#pragma unroll
                for (int u = 0; u < 4; ++u) csc[k][u] = csn[k][u];
            j += 4;
        }
        for (; j < NN; ++j) {           // 0..3 remainder columns
            float rj = M[(j - i0)*64 + t];
#pragma unroll
            for (int k = 0; k < 4; ++k)
                if (k < bs) {
                    float2 cs = csl[base[k] + j];
                    float wv = cs.y*r[k] + cs.x*rj;
                    r[k] = cs.x*r[k] - cs.y*rj;
                    rj = wv;
                }
            M[(j - i0)*64 + t] = rj;
        }
#pragma unroll
        for (int k = 0; k < 4; ++k)
            if (k < bs) M[(i + k - i0)*64 + t] = r[k];
        i += bs;
    }
    WAVE_LDS_FENCE();

    // writeout: float4 per lane; rows < i0 are identity
    for (int id = t; id < 4096; id += 64) {
        int row = id >> 4, c4 = (id & 15) * 4;
        float4 v;
        if (row < i0) {
            v = make_float4(0.f,0.f,0.f,0.f);
            int d = row - (c0 + c4);
            if (d >= 0 && d < 4) ((float*)&v)[d] = 1.0f;
        } else {
            v = *(const float4*)&M[(row - i0)*64 + c4];
        }
        *(float4*)(outp + row*NN + c0 + c4) = v;
    }
}

// ---------------- 2) tree fold body (r13-verified) --------------------------
__device__ __forceinline__ void fold_body(const float* __restrict__ in,
                                          float* __restrict__ out,
                                          int nOut, int lg, int span,
                                          int b, int t) {
    int np2 = 2 * nOut;
    int m    = b & (np2 - 1);
    int tile = b >> lg;
    int side = (m >= nOut) ? 1 : 0;
    int q = m - side * nOut;
    const float* A = in + (side*np2 + 2*q + 1) * MAT;
    const float* B = in + (side*np2 + 2*q) * MAT;
    float* C = out + m * MAT;
    int i0A = BD[q * span + (span >> 1)];
    int r0 = (tile >> 2) * 64, c0 = (tile & 3) * 64;

    if (r0 + 64 <= i0A) {           // copy tile (exact)
#pragma unroll
        for (int u = 0; u < 4; ++u) {
            int id = u*256 + t;
            int rr = id >> 4, cc = (id & 15) * 4;
            *(float4*)(C + (r0+rr)*NN + c0 + cc) =
                *(const float4*)(B + (r0+rr)*NN + c0 + cc);
        }
        return;
    }

    int kstart = ((r0 < i0A) ? r0 : i0A) & ~31;
    int nt = (NN - kstart) >> 5;

    __shared__ float Ast[2][32][68];
    __shared__ float Bs [2][32][68];
    int tx = t & 15, ty = t >> 4;
    int arow = t >> 3, ak4 = t & 7;
    int bkr = t >> 4, bc4 = t & 15;

    float acc[4][4] = {};
    f32x4 pa0, pa1, pb0, pb1;
    {
        int kt = kstart;
        pa0 = *(const f32x4*)(A + (r0 + arow     )*NN + kt + ak4*4);
        pa1 = *(const f32x4*)(A + (r0 + arow + 32)*NN + kt + ak4*4);
        pb0 = *(const f32x4*)(B + (kt + bkr      )*NN + c0 + bc4*4);
        pb1 = *(const f32x4*)(B + (kt + bkr + 16 )*NN + c0 + bc4*4);
    }
    for (int it = 0; it < nt; ++it) {
        int cur = it & 1;
#pragma unroll
        for (int jj = 0; jj < 4; ++jj) {
            Ast[cur][ak4*4 + jj][arow]      = pa0[jj];
            Ast[cur][ak4*4 + jj][arow + 32] = pa1[jj];
        }
        *(f32x4*)&Bs[cur][bkr     ][bc4*4] = pb0;
        *(f32x4*)&Bs[cur][bkr + 16][bc4*4] = pb1;
        if (it + 1 < nt) {
            int k2 = kstart + (it+1)*32;
            pa0 = *(const f32x4*)(A + (r0 + arow     )*NN + k2 + ak4*4);
            pa1 = *(const f32x4*)(A + (r0 + arow + 32)*NN + k2 + ak4*4);
            pb0 = *(const f32x4*)(B + (k2 + bkr      )*NN + c0 + bc4*4);
            pb1 = *(const f32x4*)(B + (k2 + bkr + 16 )*NN + c0 + bc4*4);
        }
        BAR();
#pragma unroll 8
        for (int kk = 0; kk < 32; ++kk) {
            f32x4 a4 = *(const f32x4*)&Ast[cur][kk][ty*4];
            f32x4 b4 = *(const f32x4*)&Bs [cur][kk][tx*4];
#pragma unroll
            for (int rr = 0; rr < 4; ++rr)
#pragma unroll
                for (int cc = 0; cc < 4; ++cc)
                    acc[rr][cc] = fmaf(a4[rr], b4[cc], acc[rr][cc]);
        }
    }
#pragma unroll
    for (int rr = 0; rr < 4; ++rr) {
        float4 o = {acc[rr][0], acc[rr][1], acc[rr][2], acc[rr][3]};
        *(float4*)(C + (r0 + ty*4 + rr)*NN + c0 + tx*4) = o;
    }
}

__global__ __launch_bounds__(256) void k_fold1(const float* in, float* out)
{ fold_body(in, out, 16, 5,  2, blockIdx.x, threadIdx.x); }
__global__ __launch_bounds__(256) void k_fold2(const float* in, float* out)
{ fold_body(in, out,  8, 4,  4, blockIdx.x, threadIdx.x); }
__global__ __launch_bounds__(256) void k_fold3(const float* in, float* out)
{ fold_body(in, out,  4, 3,  8, blockIdx.x, threadIdx.x); }
__global__ __launch_bounds__(256) void k_fold4(const float* in, float* out)
{ fold_body(in, out,  2, 2, 16, blockIdx.x, threadIdx.x); }
__global__ __launch_bounds__(256) void k_fold5(const float* in, float* out)
{ fold_body(in, out,  1, 1, 32, blockIdx.x, threadIdx.x); }

// ------- 3) Wbt[n][i] = bf16( sum_k U[i][k] S[k] V[n][k] ), 256 blocks -------
__global__ __launch_bounds__(256) void k_wmatT(const float* __restrict__ U,
                                               const float* __restrict__ V,
                                               const float* __restrict__ S,
                                               unsigned short* __restrict__ Wbt) {
    int b = blockIdx.x;
    int n0 = (b >> 4) * 16, i0 = (b & 15) * 16;
    int t = threadIdx.x, ti = t & 15, tn = t >> 4;
    __shared__ float Us[16][260];
    __shared__ float Vs[16][260];
    {
        int rr = t >> 4, cc = (t & 15) * 16;
#pragma unroll
        for (int q = 0; q < 4; ++q) {
            float4 u = *(const float4*)(U + (i0+rr)*NN + cc + q*4);
            float4 s = *(const float4*)(S + cc + q*4);
            u.x *= s.x; u.y *= s.y; u.z *= s.z; u.w *= s.w;
            *(float4*)&Us[rr][cc+q*4] = u;
            *(float4*)&Vs[rr][cc+q*4] = *(const float4*)(V + (n0+rr)*NN + cc + q*4);
        }
    }
    __syncthreads();
    float acc = 0.f;
#pragma unroll 8
    for (int k4 = 0; k4 < 64; ++k4) {
        float4 uu = *(const float4*)&Us[ti][k4*4];
        float4 vv = *(const float4*)&Vs[tn][k4*4];
        acc += uu.x*vv.x + uu.y*vv.y + uu.z*vv.z + uu.w*vv.w;
    }
    Wbt[(n0+tn)*NN + (i0+ti)] = (unsigned short)f2bf(acc);
}

// ---------------- 4a) k_mm_bf: out = xbf @ W + bias (bf16 x, half reads) ----
__global__ __launch_bounds__(512, 4) void k_mm_bf(const unsigned short* __restrict__ xbf,
                                                  const unsigned short* __restrict__ Wbt,
                                                  const float* __restrict__ bias,
                                                  float* __restrict__ out) {
    int t = threadIdx.x;
    int w = t >> 6, l = t & 63, l15 = l & 15, lg = l >> 4;
    int n0 = w * 32;

    __shared__ unsigned short Xs[2][8 * 512];

    long rowbase = (long)blockIdx.x * 256;
    int r = t & 15, m = t >> 4;
    int ksb = m >> 2;
    int lidx = r + 16 * (m & 3);

    const unsigned short* s0 = xbf + (rowbase + r) * NN + 8*m;
    short8 f = *(const short8*)(s0);

    short8 bfrag[2][8];
#pragma unroll
    for (int nt = 0; nt < 2; ++nt) {
        const unsigned short* wrow = Wbt + (n0 + nt*16 + l15) * NN + lg * 8;
#pragma unroll
        for (int ks = 0; ks < 8; ++ks)
            bfrag[nt][ks] = *(const short8*)(wrow + ks * 32);
    }
    float b0 = bias[n0 + l15];
    float b1 = bias[n0 + 16 + l15];

    for (int it = 0; it < 16; ++it) {
        int cur = it & 1;
        *(short8*)&Xs[cur][ksb*512 + lidx*8] = f;
        if (it < 15) {
            const unsigned short* sn = xbf + (rowbase + (it+1)*16 + r) * NN + 8*m;
            f = *(const short8*)(sn);
        }
        BAR();

        f32x4 acc0 = {0.f,0.f,0.f,0.f}, acc1 = {0.f,0.f,0.f,0.f};
#pragma unroll
        for (int ks = 0; ks < 8; ++ks) {
            short8 af = *(const short8*)&Xs[cur][ks*512 + l*8];
            acc0 = __builtin_amdgcn_mfma_f32_16x16x32_bf16(af, bfrag[0][ks], acc0, 0, 0, 0);
            acc1 = __builtin_amdgcn_mfma_f32_16x16x32_bf16(af, bfrag[1][ks], acc1, 0, 0, 0);
        }
        float* op = out + (rowbase + it*16 + lg*4) * NN + n0 + l15;
#pragma unroll
        for (int rr = 0; rr < 4; ++rr) {
            __builtin_nontemporal_store(acc0[rr] + b0, op + rr * NN);
            __builtin_nontemporal_store(acc1[rr] + b1, op + rr * NN + 16);
        }
    }
}

// ---------------- 4b) k_mm: fallback (f32 x, on-the-fly cvt; r21) -----------
__global__ __launch_bounds__(512, 4) void k_mm(const float* __restrict__ x,
                                               const unsigned short* __restrict__ Wbt,
                                               const float* __restrict__ bias,
                                               float* __restrict__ out) {
    int t = threadIdx.x;
    int w = t >> 6, l = t & 63, l15 = l & 15, lg = l >> 4;
    int n0 = w * 32;

    __shared__ unsigned short Xs[2][8 * 512];

    long rowbase = (long)blockIdx.x * 256;
    int r = t & 15, m = t >> 4;
    int ksb = m >> 2;
    int lidx = r + 16 * (m & 3);

    const float* s0 = x + (rowbase + r) * NN + 8*m;
    float4 f0 = *(const float4*)(s0);
    float4 f1 = *(const float4*)(s0 + 4);

    short8 bfrag[2][8];
#pragma unroll
    for (int nt = 0; nt < 2; ++nt) {
        const unsigned short* wrow = Wbt + (n0 + nt*16 + l15) * NN + lg * 8;
#pragma unroll
        for (int ks = 0; ks < 8; ++ks)
            bfrag[nt][ks] = *(const short8*)(wrow + ks * 32);
    }
    float b0 = bias[n0 + l15];
    float b1 = bias[n0 + 16 + l15];

    for (int it = 0; it < 16; ++it) {
        int cur = it & 1;
        short8 h;
        h[0]=f2bf(f0.x); h[1]=f2bf(f0.y); h[2]=f2bf(f0.z); h[3]=f2bf(f0.w);
        h[4]=f2bf(f1.x); h[5]=f2bf(f1.y); h[6]=f2bf(f1.z); h[7]=f2bf(f1.w);
        *(short8*)&Xs[cur][ksb*512 + lidx*8] = h;
        if (it < 15) {
            const float* sn = x + (rowbase + (it+1)*16 + r) * NN + 8*m;
            f0 = *(const float4*)(sn);
            f1 = *(const float4*)(sn + 4);
        }
        BAR();

        f32x4 acc0 = {0.f,0.f,0.f,0.f}, acc1 = {0.f,0.f,0.f,0.f};
#pragma unroll
        for (int ks = 0; ks < 8; ++ks) {
            short8 af = *(const short8*)&Xs[cur][ks*512 + l*8];
            acc0 = __builtin_amdgcn_mfma_f32_16x16x32_bf16(af, bfrag[0][ks], acc0, 0, 0, 0);
            acc1 = __builtin_amdgcn_mfma_f32_16x16x32_bf16(af, bfrag[1][ks], acc1, 0, 0, 0);
        }
        float* op = out + (rowbase + it*16 + lg*4) * NN + n0 + l15;
#pragma unroll
        for (int rr = 0; rr < 4; ++rr) {
            __builtin_nontemporal_store(acc0[rr] + b0, op + rr * NN);
            __builtin_nontemporal_store(acc1[rr] + b1, op + rr * NN + 16);
        }
    }
}

extern "C" void kernel_launch(void* const* d_in, const int* in_sizes, int n_in,
                              void* d_out, int out_size, void* d_ws, size_t ws_size,
                              hipStream_t stream) {
    const float* x    = (const float*)d_in[0];
    const float* Uw   = (const float*)d_in[1];
    const float* Vw   = (const float*)d_in[2];
    const float* Sw   = (const float*)d_in[3];
    const float* bias = (const float*)d_in[4];
    float* out = (float*)d_out;
    float* ws  = (float*)d_ws;

    bool fused = ws_size >= (size_t)WS_NEED_FLOATS * sizeof(float);
    unsigned short* xbf = (unsigned short*)(ws + XBF_OFF);

    // rotations (wave0) + x->bf16 conversion (7 waves, TLP-covered)
    k_build<<<256, 512, 0, stream>>>(Uw, Vw, ws + MATS0, x,
                                     fused ? xbf : nullptr);
    // fold 32 -> 16 -> 8 -> 4 -> 2 -> 1 per side; final U,V land in MATS1
    k_fold1<<<16*32, 256, 0, stream>>>(ws + MATS0, ws + MATS1);
    k_fold2<<<16*16, 256, 0, stream>>>(ws + MATS1, ws + MATS0);
    k_fold3<<<16* 8, 256, 0, stream>>>(ws + MATS0, ws + MATS1);
    k_fold4<<<16* 4, 256, 0, stream>>>(ws + MATS1, ws + MATS0);
    k_fold5<<<16* 2, 256, 0, stream>>>(ws + MATS0, ws + MATS1);
    // Wbt = bf16( (U S V^T)^T ), [n][k] layout
    k_wmatT<<<256, 256, 0, stream>>>(ws + MATS1, ws + MATS1 + MAT, Sw,
                                     (unsigned short*)(ws + WBT_OFF));
    // out = x @ W + bias
    if (fused)
        k_mm_bf<<<512, 512, 0, stream>>>(xbf, (unsigned short*)(ws + WBT_OFF),
                                         bias, out);
    else
        k_mm<<<512, 512, 0, stream>>>(x, (unsigned short*)(ws + WBT_OFF),
                                      bias, out);
}

// Round 26
// 188.708 us; speedup vs baseline: 1.0574x; 1.0574x over previous
//
#include <hip/hip_runtime.h>
#include <hip/hip_bf16.h>
#include <math.h>

#define NN 256
#define NSEG 32
#define MAT (NN*NN)            // 65536 floats

// float offsets inside d_ws (~25.2 MB)
#define MATS0 0                        // 64 leaf matrices (U:0..31, V:32..63)
#define MATS1 (MATS0 + 64*MAT)         // 32 matrices; final U,V land here
#define WBT_OFF (MATS1 + 32*MAT)       // 65536 ushort (bf16 W^T[n][k])

// sweep boundaries: segment g = sweeps [BD[g], BD[g+1]); nrot <= 1120.
static __device__ const int BD[NSEG+1] =
    {0,4,8,12,16,20,24,28,32,37,42,47,52,57,62,67,73,79,85,91,97,
     104,111,118,126,134,143,153,164,177,192,213,255};
#define CSL_CAP 1120

typedef __attribute__((ext_vector_type(8))) short short8;
typedef __attribute__((ext_vector_type(4))) float f32x4;

__device__ __forceinline__ short f2bf(float f) {
    __hip_bfloat16 h = __float2bfloat16(f);   // RNE
    return *reinterpret_cast<short*>(&h);
}

// Raw block barrier: flushes LDS but does NOT drain vmcnt.
#define BAR() do {                                              \
    asm volatile("s_waitcnt lgkmcnt(0)" ::: "memory");          \
    __builtin_amdgcn_s_barrier();                               \
    asm volatile("" ::: "memory");                              \
} while (0)

// ---------------- 1) segment partial products: 4-SWEEP BLOCKS ---------------
// Rows i..i+3 in registers; per column j: 1 LDS read, 4 register rotations,
// 1 LDS write. Lex order preserved (head triangle first; ascending j;
// (a,j) before (a',j) for a<a'). Chunk-clip exact (clipped entries are 0).
__global__ __launch_bounds__(64) void k_build(const float* __restrict__ au,
                                              const float* __restrict__ av,
                                              float* __restrict__ mats) {
    int b = blockIdx.x;
    int matid = b >> 7;          // 0=U, 1=V
    int seg   = (b >> 2) & 31;
    int chunk = b & 3;
    int t = threadIdx.x;         // 0..63
    int c0 = chunk * 64;
    int i0 = BD[seg], i1 = BD[seg+1];
    float* outp = mats + (matid * NSEG + seg) * MAT;

    if (c0 + 64 <= i0) {         // whole chunk is identity columns
        for (int id = t; id < 4096; id += 64) {
            int row = id >> 4, c4 = (id & 15) * 4;
            float4 v = {0.f,0.f,0.f,0.f};
            int d = row - (c0 + c4);
            if (d >= 0 && d < 4) ((float*)&v)[d] = 1.0f;
            *(float4*)(outp + row*NN + c0 + c4) = v;
        }
        return;
    }

    __shared__ float M[NN * 64];       // rows [i0,256) x 64 cols
    __shared__ float2 csl[CSL_CAP];    // segment cos/sin table

    int kbase = 255*i0 - (i0*(i0-1))/2;
    int kend  = 255*i1 - (i1*(i1-1))/2;
    int nrot  = kend - kbase;
    const float* ang = (matid ? av : au) + kbase;
    for (int idx = t; idx < nrot; idx += 64) {
        float s, c;
        sincosf(ang[idx], &s, &c);
        float2 v = {c, s};
        csl[idx] = v;
    }
    int MR = NN - i0;
    for (int rr = 0; rr < MR; ++rr)
        M[rr*64 + t] = (i0 + rr == c0 + t) ? 1.0f : 0.0f;
    __syncthreads();

    int i = i0;
    while (i < i1) {
        int bs = i1 - i; if (bs > 4) bs = 4;
        float r[4];
#pragma unroll
        for (int k = 0; k < 4; ++k)
            if (k < bs) r[k] = M[(i + k - i0)*64 + t];

        // head triangle (register-only), lex order, chunk-clip guard
#pragma unroll
        for (int a = 0; a < 3; ++a)
#pragma unroll
            for (int b2 = a + 1; b2 < 4; ++b2)
                if (b2 < bs && i + b2 >= c0) {
                    int aa = i + a;
                    int idx = 255*aa - (aa*(aa-1))/2 + (b2 - a - 1) - kbase;
                    float2 cs = csl[idx];
                    float wv = cs.y*r[a] + cs.x*r[b2];
                    r[a]  = cs.x*r[a] - cs.y*r[b2];
                    r[b2] = wv;
                }

        int jblk = i + bs; if (jblk < c0) jblk = c0;
        int base[4];
#pragma unroll
        for (int k = 0; k < 4; ++k) {
            int a = i + k;
            base[k] = 255*a - (a*(a-1))/2 - a - 1 - kbase;
        }

        int j = jblk;
        int ngr = (NN - jblk) >> 2;
        float rjc[4]; float2 csc[4][4];
        if (ngr > 0) {
#pragma unroll
            for (int u = 0; u < 4; ++u) rjc[u] = M[(j + u - i0)*64 + t];
#pragma unroll
            for (int k = 0; k < 4; ++k)
                if (k < bs)
#pragma unroll
                    for (int u = 0; u < 4; ++u)
                        csc[k][u] = csl[base[k] + j + u];
        }
        for (int g = 0; g < ngr; ++g) {
            float rjn[4]; float2 csn[4][4];
            if (g + 1 < ngr) {          // prefetch next column group
#pragma unroll
                for (int u = 0; u < 4; ++u) rjn[u] = M[(j + 4 + u - i0)*64 + t];
#pragma unroll
                for (int k = 0; k < 4; ++k)
                    if (k < bs)
#pragma unroll
                        for (int u = 0; u < 4; ++u)
                            csn[k][u] = csl[base[k] + j + 4 + u];
            }
#pragma unroll
            for (int u = 0; u < 4; ++u) {
                float rj = rjc[u];
#pragma unroll
                for (int k = 0; k < 4; ++k)
                    if (k < bs) {
                        float2 cs = csc[k][u];
                        float wv = cs.y*r[k] + cs.x*rj;
                        r[k] = cs.x*r[k] - cs.y*rj;
                        rj = wv;
                    }
                M[(j + u - i0)*64 + t] = rj;
            }
#pragma unroll
            for (int u = 0; u < 4; ++u) rjc[u] = rjn[u];
#pragma unroll
            for (int k = 0; k < 4; ++k)
#pragma unroll
                for (int u = 0; u < 4; ++u) csc[k][u] = csn[k][u];
            j += 4;
        }
        for (; j < NN; ++j) {           // 0..3 remainder columns
            float rj = M[(j - i0)*64 + t];
#pragma unroll
            for (int k = 0; k < 4; ++k)
                if (k < bs) {
                    float2 cs = csl[base[k] + j];
                    float wv = cs.y*r[k] + cs.x*rj;
                    r[k] = cs.x*r[k] - cs.y*rj;
                    rj = wv;
                }
            M[(j - i0)*64 + t] = rj;
        }
#pragma unroll
        for (int k = 0; k < 4; ++k)
            if (k < bs) M[(i + k - i0)*64 + t] = r[k];
        i += bs;
    }
    __syncthreads();

    // writeout: float4 per lane; rows < i0 are identity
    for (int id = t; id < 4096; id += 64) {
        int row = id >> 4, c4 = (id & 15) * 4;
        float4 v;
        if (row < i0) {
            v = make_float4(0.f,0.f,0.f,0.f);
            int d = row - (c0 + c4);
            if (d >= 0 && d < 4) ((float*)&v)[d] = 1.0f;
        } else {
            v = *(const float4*)&M[(row - i0)*64 + c4];
        }
        *(float4*)(outp + row*NN + c0 + c4) = v;
    }
}

// ---------------- 2) tree fold body (r13-verified) --------------------------
__device__ __forceinline__ void fold_body(const float* __restrict__ in,
                                          float* __restrict__ out,
                                          int nOut, int lg, int span,
                                          int b, int t) {
    int np2 = 2 * nOut;
    int m    = b & (np2 - 1);
    int tile = b >> lg;
    int side = (m >= nOut) ? 1 : 0;
    int q = m - side * nOut;
    const float* A = in + (side*np2 + 2*q + 1) * MAT;
    const float* B = in + (side*np2 + 2*q) * MAT;
    float* C = out + m * MAT;
    int i0A = BD[q * span + (span >> 1)];
    int r0 = (tile >> 2) * 64, c0 = (tile & 3) * 64;

    if (r0 + 64 <= i0A) {           // copy tile (exact)
#pragma unroll
        for (int u = 0; u < 4; ++u) {
            int id = u*256 + t;
            int rr = id >> 4, cc = (id & 15) * 4;
            *(float4*)(C + (r0+rr)*NN + c0 + cc) =
                *(const float4*)(B + (r0+rr)*NN + c0 + cc);
        }
        return;
    }

    int kstart = ((r0 < i0A) ? r0 : i0A) & ~31;
    int nt = (NN - kstart) >> 5;

    __shared__ float Ast[2][32][68];
    __shared__ float Bs [2][32][68];
    int tx = t & 15, ty = t >> 4;
    int arow = t >> 3, ak4 = t & 7;
    int bkr = t >> 4, bc4 = t & 15;

    float acc[4][4] = {};
    f32x4 pa0, pa1, pb0, pb1;
    {
        int kt = kstart;
        pa0 = *(const f32x4*)(A + (r0 + arow     )*NN + kt + ak4*4);
        pa1 = *(const f32x4*)(A + (r0 + arow + 32)*NN + kt + ak4*4);
        pb0 = *(const f32x4*)(B + (kt + bkr      )*NN + c0 + bc4*4);
        pb1 = *(const f32x4*)(B + (kt + bkr + 16 )*NN + c0 + bc4*4);
    }
    for (int it = 0; it < nt; ++it) {
        int cur = it & 1;
#pragma unroll
        for (int jj = 0; jj < 4; ++jj) {
            Ast[cur][ak4*4 + jj][arow]      = pa0[jj];
            Ast[cur][ak4*4 + jj][arow + 32] = pa1[jj];
        }
        *(f32x4*)&Bs[cur][bkr     ][bc4*4] = pb0;
        *(f32x4*)&Bs[cur][bkr + 16][bc4*4] = pb1;
        if (it + 1 < nt) {
            int k2 = kstart + (it+1)*32;
            pa0 = *(const f32x4*)(A + (r0 + arow     )*NN + k2 + ak4*4);
            pa1 = *(const f32x4*)(A + (r0 + arow + 32)*NN + k2 + ak4*4);
            pb0 = *(const f32x4*)(B + (k2 + bkr      )*NN + c0 + bc4*4);
            pb1 = *(const f32x4*)(B + (k2 + bkr + 16 )*NN + c0 + bc4*4);
        }
        BAR();
#pragma unroll 8
        for (int kk = 0; kk < 32; ++kk) {
            f32x4 a4 = *(const f32x4*)&Ast[cur][kk][ty*4];
            f32x4 b4 = *(const f32x4*)&Bs [cur][kk][tx*4];
#pragma unroll
            for (int rr = 0; rr < 4; ++rr)
#pragma unroll
                for (int cc = 0; cc < 4; ++cc)
                    acc[rr][cc] = fmaf(a4[rr], b4[cc], acc[rr][cc]);
        }
    }
#pragma unroll
    for (int rr = 0; rr < 4; ++rr) {
        float4 o = {acc[rr][0], acc[rr][1], acc[rr][2], acc[rr][3]};
        *(float4*)(C + (r0 + ty*4 + rr)*NN + c0 + tx*4) = o;
    }
}

__global__ __launch_bounds__(256) void k_fold1(const float* in, float* out)
{ fold_body(in, out, 16, 5,  2, blockIdx.x, threadIdx.x); }
__global__ __launch_bounds__(256) void k_fold2(const float* in, float* out)
{ fold_body(in, out,  8, 4,  4, blockIdx.x, threadIdx.x); }
__global__ __launch_bounds__(256) void k_fold3(const float* in, float* out)
{ fold_body(in, out,  4, 3,  8, blockIdx.x, threadIdx.x); }
__global__ __launch_bounds__(256) void k_fold4(const float* in, float* out)
{ fold_body(in, out,  2, 2, 16, blockIdx.x, threadIdx.x); }
__global__ __launch_bounds__(256) void k_fold5(const float* in, float* out)
{ fold_body(in, out,  1, 1, 32, blockIdx.x, threadIdx.x); }

// ------- 3) Wbt[n][i] = bf16( sum_k U[i][k] S[k] V[n][k] ), 256 blocks -------
__global__ __launch_bounds__(256) void k_wmatT(const float* __restrict__ U,
                                               const float* __restrict__ V,
                                               const float* __restrict__ S,
                                               unsigned short* __restrict__ Wbt) {
    int b = blockIdx.x;
    int n0 = (b >> 4) * 16, i0 = (b & 15) * 16;
    int t = threadIdx.x, ti = t & 15, tn = t >> 4;
    __shared__ float Us[16][260];
    __shared__ float Vs[16][260];
    {
        int rr = t >> 4, cc = (t & 15) * 16;
#pragma unroll
        for (int q = 0; q < 4; ++q) {
            float4 u = *(const float4*)(U + (i0+rr)*NN + cc + q*4);
            float4 s = *(const float4*)(S + cc + q*4);
            u.x *= s.x; u.y *= s.y; u.z *= s.z; u.w *= s.w;
            *(float4*)&Us[rr][cc+q*4] = u;
            *(float4*)&Vs[rr][cc+q*4] = *(const float4*)(V + (n0+rr)*NN + cc + q*4);
        }
    }
    __syncthreads();
    float acc = 0.f;
#pragma unroll 8
    for (int k4 = 0; k4 < 64; ++k4) {
        float4 uu = *(const float4*)&Us[ti][k4*4];
        float4 vv = *(const float4*)&Vs[tn][k4*4];
        acc += uu.x*vv.x + uu.y*vv.y + uu.z*vv.z + uu.w*vv.w;
    }
    Wbt[(n0+tn)*NN + (i0+ti)] = (unsigned short)f2bf(acc);
}

// ---------------- 4) out = x @ W + bias : bf16 MFMA + nt stores -------------
// Measured plateau: 7 structural variants all ~80us; interleaved 268MB r/w
// stream with L3 thrash (FETCH constant 66MB); bytes contractually fixed.
__global__ __launch_bounds__(512, 4) void k_mm(const float* __restrict__ x,
                                               const unsigned short* __restrict__ Wbt,
                                               const float* __restrict__ bias,
                                               float* __restrict__ out) {
    int t = threadIdx.x;
    int w = t >> 6, l = t & 63, l15 = l & 15, lg = l >> 4;
    int n0 = w * 32;

    __shared__ unsigned short Xs[2][8 * 512];

    long rowbase = (long)blockIdx.x * 256;
    int r = t & 15, m = t >> 4;
    int ksb = m >> 2;
    int lidx = r + 16 * (m & 3);

    const float* s0 = x + (rowbase + r) * NN + 8*m;
    float4 f0 = *(const float4*)(s0);
    float4 f1 = *(const float4*)(s0 + 4);

    short8 bfrag[2][8];
#pragma unroll
    for (int nt = 0; nt < 2; ++nt) {
        const unsigned short* wrow = Wbt + (n0 + nt*16 + l15) * NN + lg * 8;
#pragma unroll
        for (int ks = 0; ks < 8; ++ks)
            bfrag[nt][ks] = *(const short8*)(wrow + ks * 32);
    }
    float b0 = bias[n0 + l15];
    float b1 = bias[n0 + 16 + l15];

    for (int it = 0; it < 16; ++it) {
        int cur = it & 1;
        short8 h;
        h[0]=f2bf(f0.x); h[1]=f2bf(f0.y); h[2]=f2bf(f0.z); h[3]=f2bf(f0.w);
        h[4]=f2bf(f1.x); h[5]=f2bf(f1.y); h[6]=f2bf(f1.z); h[7]=f2bf(f1.w);
        *(short8*)&Xs[cur][ksb*512 + lidx*8] = h;
        if (it < 15) {
            const float* sn = x + (rowbase + (it+1)*16 + r) * NN + 8*m;
            f0 = *(const float4*)(sn);
            f1 = *(const float4*)(sn + 4);
        }
        BAR();

        f32x4 acc0 = {0.f,0.f,0.f,0.f}, acc1 = {0.f,0.f,0.f,0.f};
#pragma unroll
        for (int ks = 0; ks < 8; ++ks) {
            short8 af = *(const short8*)&Xs[cur][ks*512 + l*8];
            acc0 = __builtin_amdgcn_mfma_f32_16x16x32_bf16(af, bfrag[0][ks], acc0, 0, 0, 0);
            acc1 = __builtin_amdgcn_mfma_f32_16x16x32_bf16(af, bfrag[1][ks], acc1, 0, 0, 0);
        }
        float* op = out + (rowbase + it*16 + lg*4) * NN + n0 + l15;
#pragma unroll
        for (int rr = 0; rr < 4; ++rr) {
            __builtin_nontemporal_store(acc0[rr] + b0, op + rr * NN);
            __builtin_nontemporal_store(acc1[rr] + b1, op + rr * NN + 16);
        }
    }
}

extern "C" void kernel_launch(void* const* d_in, const int* in_sizes, int n_in,
                              void* d_out, int out_size, void* d_ws, size_t ws_size,
                              hipStream_t stream) {
    const float* x    = (const float*)d_in[0];
    const float* Uw   = (const float*)d_in[1];
    const float* Vw   = (const float*)d_in[2];
    const float* Sw   = (const float*)d_in[3];
    const float* bias = (const float*)d_in[4];
    float* out = (float*)d_out;
    float* ws  = (float*)d_ws;

    // 32 sweep-aligned segment products per matrix (4-sweep-blocked rotations)
    k_build<<<256, 64, 0, stream>>>(Uw, Vw, ws + MATS0);
    // fold 32 -> 16 -> 8 -> 4 -> 2 -> 1 per side; final U,V land in MATS1
    k_fold1<<<16*32, 256, 0, stream>>>(ws + MATS0, ws + MATS1);
    k_fold2<<<16*16, 256, 0, stream>>>(ws + MATS1, ws + MATS0);
    k_fold3<<<16* 8, 256, 0, stream>>>(ws + MATS0, ws + MATS1);
    k_fold4<<<16* 4, 256, 0, stream>>>(ws + MATS1, ws + MATS0);
    k_fold5<<<16* 2, 256, 0, stream>>>(ws + MATS0, ws + MATS1);
    // Wbt = bf16( (U S V^T)^T ), [n][k] layout
    k_wmatT<<<256, 256, 0, stream>>>(ws + MATS1, ws + MATS1 + MAT, Sw,
                                     (unsigned short*)(ws + WBT_OFF));
    // out = x @ W + bias (bf16 MFMA, nontemporal stores)
    k_mm<<<512, 512, 0, stream>>>(x, (unsigned short*)(ws + WBT_OFF), bias, out);
}